// Round 4
// baseline (361.103 us; speedup 1.0000x reference)
//
#include <hip/hip_runtime.h>
#include <math.h>

#define IN_DIM 28
#define BOND   10
#define OUT_D  10
#define BLOCK  256
#define THRESH 35.0f   // sigmoid(c)==1.0f in fp32 for c>~17.4; 2x margin

// Weight-only preprocessing results, computed once per launch by prep_kernel.
// [0..27]  v[i]  = min_b t0[i][b]
// [28..55] u[j]  = min_o sum_b t1[j][b][o]
// [56]     biasmin = min_o bias[o]
// [57]     wneg    = 1.0f if any weight < 0 (bound invalid -> exact path)
__device__ __align__(16) float g_prep[64];

__global__ void prep_kernel(const float* __restrict__ t0,
                            const float* __restrict__ t1,
                            const float* __restrict__ bias)
{
    const int tid = threadIdx.x;   // 64 threads, 1 block
    if (tid < IN_DIM) {
        // v[i] = min_b t0[i][b]
        const float* __restrict__ p = t0 + tid * BOND;
        float m = p[0];
#pragma unroll
        for (int b = 1; b < BOND; ++b) m = fminf(m, p[b]);
        g_prep[tid] = m;
        // u[j] = min_o sum_b t1[j][b][o]
        const float* __restrict__ q = t1 + tid * (BOND * OUT_D);
        float mu = 3.4e38f;
#pragma unroll
        for (int o = 0; o < OUT_D; ++o) {
            float s = 0.0f;
#pragma unroll
            for (int b = 0; b < BOND; ++b) s += q[b * OUT_D + o];
            mu = fminf(mu, s);
        }
        g_prep[IN_DIM + tid] = mu;
    }
    // any-negative-weight scan (validity precondition for the bound)
    int ln = 0;
    for (int idx = tid; idx < IN_DIM * BOND; idx += 64)
        ln |= (t0[idx] < 0.0f);
    for (int idx = tid; idx < IN_DIM * BOND * OUT_D; idx += 64)
        ln |= (t1[idx] < 0.0f);
    const bool anyneg = __any(ln);
    if (tid == 0) {
        float bm = bias[0];
#pragma unroll
        for (int o = 1; o < OUT_D; ++o) bm = fminf(bm, bias[o]);
        g_prep[56] = bm;
        g_prep[57] = anyneg ? 1.0f : 0.0f;
    }
}

// One thread = one sample. Fast path (validated by per-sample check):
//   all x >= 0 and all weights >= 0  =>
//   c[o]+bias[o] >= A*B + biasmin,  A = x0.v,  B = x1.u
// If A*B+biasmin > THRESH for every lane of the wave, every output is
// provably exactly 1.0f (fp32 sigmoid saturation) -> 3 coalesced float4
// stores of 1.0f. Otherwise the wave computes the exact einsum from global
// weights (statistically never on this benchmark; keeps correctness for
// arbitrary inputs).
//
// No LDS, no __syncthreads: all weight-derived values come from g_prep at
// wave-uniform compile-time offsets -> s_load into SGPRs, consumed directly
// as the scalar operand of v_fmac_f32.
__global__ __launch_bounds__(BLOCK) void tn_kernel(
    const float* __restrict__ x,     // [N, 56]
    const float* __restrict__ t0,    // [28,10]   (i,b)
    const float* __restrict__ t1,    // [28,10,10](j,b,o)
    const float* __restrict__ bias,  // [10]
    float* __restrict__ out,         // [N,10]
    int n_total)
{
    const int tid = threadIdx.x;
    const int n = blockIdx.x * BLOCK + tid;
    const int nc = (n < n_total) ? n : (n_total - 1);   // clamp loads; stores guarded

    // ---- this sample's 56 floats (14 float4; row = 224 B, 16-aligned) ----
    float4 xq[14];
    const float4* __restrict__ xrow =
        reinterpret_cast<const float4*>(x + (size_t)nc * (2 * IN_DIM));
#pragma unroll
    for (int k = 0; k < 14; ++k) xq[k] = xrow[k];

    // ---- tier-1 bound: A = x0.v, B = x1.u, track xmin for validity ----
    float A = 0.0f, B = 0.0f, xmin = 0.0f;
#pragma unroll
    for (int k = 0; k < 7; ++k) {
        const float4 q = xq[k];
        A = fmaf(q.x, g_prep[4 * k + 0], A);
        A = fmaf(q.y, g_prep[4 * k + 1], A);
        A = fmaf(q.z, g_prep[4 * k + 2], A);
        A = fmaf(q.w, g_prep[4 * k + 3], A);
        xmin = fminf(xmin, fminf(fminf(q.x, q.y), fminf(q.z, q.w)));
    }
#pragma unroll
    for (int k = 7; k < 14; ++k) {
        const float4 q = xq[k];
        B = fmaf(q.x, g_prep[4 * k + 0], B);
        B = fmaf(q.y, g_prep[4 * k + 1], B);
        B = fmaf(q.z, g_prep[4 * k + 2], B);
        B = fmaf(q.w, g_prep[4 * k + 3], B);
        xmin = fminf(xmin, fminf(fminf(q.x, q.y), fminf(q.z, q.w)));
    }

    const bool sat = (xmin >= 0.0f) && (g_prep[57] == 0.0f) &&
                     (fmaf(A, B, g_prep[56]) > THRESH);

    if (__all(sat)) {
        // Whole wave saturated: its 64 rows are a contiguous, 16B-aligned
        // 2560 B region (64*40B; base = wbase*40, wbase % 64 == 0).
        const int wbase = n & ~63;
        const int l = tid & 63;
        if (wbase + 63 < n_total) {
            float4* __restrict__ wp =
                reinterpret_cast<float4*>(out + (size_t)wbase * OUT_D);
            const float4 one4 = make_float4(1.0f, 1.0f, 1.0f, 1.0f);
            wp[l] = one4;                 // 160 float4 total: 64 + 64 + 32
            wp[64 + l] = one4;
            if (l < 32) wp[128 + l] = one4;
        } else if (n < n_total) {
            float2* __restrict__ op =
                reinterpret_cast<float2*>(out + (size_t)n * OUT_D);
            const float2 one2 = make_float2(1.0f, 1.0f);
#pragma unroll
            for (int q = 0; q < 5; ++q) op[q] = one2;
        }
        return;
    }

    // ================= exact path (statistically never taken) =================
    // Weight addresses depend only on kernel args + rolled counter b -> the
    // reads are wave-uniform (L2-hit). All register indices compile-time.
    float xe[2 * IN_DIM];
#pragma unroll
    for (int k = 0; k < 14; ++k) {
        xe[4 * k + 0] = xq[k].x;
        xe[4 * k + 1] = xq[k].y;
        xe[4 * k + 2] = xq[k].z;
        xe[4 * k + 3] = xq[k].w;
    }

    float acc[OUT_D];
#pragma unroll
    for (int o = 0; o < OUT_D; ++o) acc[o] = bias[o];

#pragma unroll 1
    for (int b = 0; b < BOND; ++b) {
        // hb = sum_i x0[i] * t0[i][b]
        const float* __restrict__ w0b = t0 + b;
        float hb = 0.0f;
#pragma unroll
        for (int i = 0; i < IN_DIM; ++i)
            hb = fmaf(xe[i], w0b[i * BOND], hb);

        // h1[o] = sum_j x1[j] * t1[j][b][o]
        const float* __restrict__ wb = t1 + b * OUT_D;
        float h1[OUT_D];
#pragma unroll
        for (int o = 0; o < OUT_D; ++o) h1[o] = 0.0f;
#pragma unroll
        for (int j = 0; j < IN_DIM; ++j) {
            const float x1j = xe[IN_DIM + j];
#pragma unroll
            for (int o = 0; o < OUT_D; ++o)
                h1[o] = fmaf(x1j, wb[j * (BOND * OUT_D) + o], h1[o]);
        }
#pragma unroll
        for (int o = 0; o < OUT_D; ++o) acc[o] = fmaf(hb, h1[o], acc[o]);
    }

    if (n < n_total) {
        float2* __restrict__ op =
            reinterpret_cast<float2*>(out + (size_t)n * OUT_D);
#pragma unroll
        for (int o = 0; o < OUT_D; o += 2) {
            float2 r;
            r.x = 1.0f / (1.0f + __expf(-acc[o]));
            r.y = 1.0f / (1.0f + __expf(-acc[o + 1]));
            op[o >> 1] = r;
        }
    }
}

extern "C" void kernel_launch(void* const* d_in, const int* in_sizes, int n_in,
                              void* d_out, int out_size, void* d_ws, size_t ws_size,
                              hipStream_t stream) {
    const float* x    = (const float*)d_in[0];
    const float* t0   = (const float*)d_in[1];
    const float* t1   = (const float*)d_in[2];
    const float* bias = (const float*)d_in[3];
    float* out        = (float*)d_out;

    const int n_total = in_sizes[0] / (2 * IN_DIM);
    const int grid = (n_total + BLOCK - 1) / BLOCK;

    prep_kernel<<<1, 64, 0, stream>>>(t0, t1, bias);
    tn_kernel<<<grid, BLOCK, 0, stream>>>(x, t0, t1, bias, out, n_total);
}